// Round 8
// baseline (17444.786 us; speedup 1.0000x reference)
//
#include <hip/hip_runtime.h>

#define WGSZ 1024
#define NWG  64

namespace {
constexpr int kN = 2048, kH = 256, kOO = 4096, kGW = 512;
}

// np.argmin(|centers - v|), first index on tie; centers in exact np fp32 order.
__device__ __forceinline__ int bin_idx(float v) {
  float t = fmaf(v, 5.0f, 63.5f);
  int i0 = (int)floorf(t);
  int c0 = i0 - 1; c0 = c0 < 0 ? 0 : (c0 > 127 ? 127 : c0);
  int c1 = i0;     c1 = c1 < 0 ? 0 : (c1 > 127 ? 127 : c1);
  int c2 = i0 + 1; c2 = c2 < 0 ? 0 : (c2 > 127 ? 127 : c2);
  float d0 = fabsf(__fmul_rn(__fadd_rn((float)(c0 - 64), 0.5f), 0.2f) - v);
  float d1 = fabsf(__fmul_rn(__fadd_rn((float)(c1 - 64), 0.5f), 0.2f) - v);
  float d2 = fabsf(__fmul_rn(__fadd_rn((float)(c2 - 64), 0.5f), 0.2f) - v);
  int best = c0; float bd = d0;
  if (d1 < bd) { bd = d1; best = c1; }
  if (d2 < bd) { bd = d2; best = c2; }
  return best;
}

// numpy pairwise_sum, exact replication for n=128.
__device__ __forceinline__ float np_pw128(const float* a) {
  float r0=a[0],r1=a[1],r2=a[2],r3=a[3],r4=a[4],r5=a[5],r6=a[6],r7=a[7];
  for (int i = 8; i < 128; i += 8) {
    r0=__fadd_rn(r0,a[i+0]); r1=__fadd_rn(r1,a[i+1]);
    r2=__fadd_rn(r2,a[i+2]); r3=__fadd_rn(r3,a[i+3]);
    r4=__fadd_rn(r4,a[i+4]); r5=__fadd_rn(r5,a[i+5]);
    r6=__fadd_rn(r6,a[i+6]); r7=__fadd_rn(r7,a[i+7]);
  }
  return __fadd_rn(__fadd_rn(__fadd_rn(r0,r1),__fadd_rn(r2,r3)),
                   __fadd_rn(__fadd_rn(r4,r5),__fadd_rn(r6,r7)));
}
__device__ __forceinline__ float np_sum256(const float* a) {
  return __fadd_rn(np_pw128(a), np_pw128(a + 128));
}

__device__ __forceinline__ float sig_np(float x) {
  return __fdiv_rn(1.0f, __fadd_rn(1.0f, expf(-x)));
}

// Exact ascending-k K=256 dot; float4 loads, identical op order to scalar chain.
__device__ __forceinline__ float dot256(const float* __restrict__ w, const float* x) {
  const float4* w4 = (const float4*)w;
  const float4* x4 = (const float4*)x;
  float acc = 0.0f;
  #pragma unroll
  for (int i = 0; i < 64; ++i) {
    float4 wv = w4[i], xv = x4[i];
    acc = fmaf(wv.x, xv.x, acc);
    acc = fmaf(wv.y, xv.y, acc);
    acc = fmaf(wv.z, xv.z, acc);
    acc = fmaf(wv.w, xv.w, acc);
  }
  return acc;
}
// Exact ascending plain sum of 256 weights (h = ones case).
__device__ __forceinline__ float sum256(const float* __restrict__ w) {
  const float4* w4 = (const float4*)w;
  float acc = 0.0f;
  #pragma unroll
  for (int i = 0; i < 64; ++i) {
    float4 wv = w4[i];
    acc = __fadd_rn(acc, wv.x);
    acc = __fadd_rn(acc, wv.y);
    acc = __fadd_rn(acc, wv.z);
    acc = __fadd_rn(acc, wv.w);
  }
  return acc;
}

__global__ __launch_bounds__(WGSZ) void planner_kernel(
    const float* __restrict__ inp_start, const float* __restrict__ map_pts,
    const float* __restrict__ ela_w1, const float* __restrict__ ela_w2,
    const float* __restrict__ conv_w, const float* __restrict__ elm_w1,
    const float* __restrict__ elm_w2, const float* __restrict__ ebl_w1,
    const float* __restrict__ ebl_w2, const float* __restrict__ lstm_wih,
    const float* __restrict__ lstm_whh, const float* __restrict__ dm_w1,
    const float* __restrict__ dm_w2, const float* __restrict__ dv_w1,
    const float* __restrict__ dv_w2, float* __restrict__ g_out) {
  const int b   = blockIdx.x;
  const int tid = threadIdx.x;

  __shared__ unsigned s_mask[kGW];
  __shared__ __align__(16) float s_conv[kOO];   // 16KB
  __shared__ __align__(16) float s_cw[800];     // conv weights for stage (LDS)
  __shared__ __align__(16) float s_elah[kH], s_elao[kH], s_elmh[kH], s_elmo[kH];
  __shared__ __align__(16) float s_eblh[kH], s_eblo[kH];
  __shared__ __align__(16) float s_h0[kH], s_c0[kH], s_h1[kH], s_c1[kH];
  __shared__ __align__(16) float s_gate[1024];
  __shared__ __align__(16) float s_tmp[512];    // LN: d, d^2
  __shared__ __align__(16) float s_r[kH], s_dmh[kH], s_dvh[kH];
  __shared__ float s_anchor[3], s_cs[2], s_g6[6];
  __shared__ float s_mu, s_den;

  // ---- init ----
  if (tid == 0) {
    float a2 = inp_start[b * 3 + 2];
    s_anchor[0] = inp_start[b * 3 + 0];
    s_anchor[1] = inp_start[b * 3 + 1];
    s_anchor[2] = a2;
    s_cs[0] = (float)cos((double)a2);
    s_cs[1] = (float)sin((double)a2);
  }
  if (tid < 3) {
    g_out[b * 96 + tid] = inp_start[b * 3 + tid];
    g_out[6144 + b * 96 + tid] = 0.01f;
  }
  __syncthreads();

  // ================= 28 sequential steps, all batch-local =================
  for (int k = 0; k < 28; ++k) {
    const int st = k / 7, a = k % 7;
    const bool a0f = (a == 0);

    // ---- OGM + conv-weight staging ----
    for (int w = tid; w < kGW; w += WGSZ) s_mask[w] = 0u;
    for (int w = tid; w < 800; w += WGSZ) s_cw[w] = conv_w[st * 800 + w];
    __syncthreads();
    {
      float ax = s_anchor[0], ay = s_anchor[1], cc = s_cs[0], ss = s_cs[1];
      for (int n = tid; n < kN; n += WGSZ) {
        float mx = __fadd_rn(map_pts[n],      -ax);
        float my = __fadd_rn(map_pts[kN + n], -ay);
        float px = fmaf(ss, my, __fmul_rn(cc, mx));
        float py = fmaf(cc, my, -__fmul_rn(ss, mx));
        bool outb = (fabsf(px) > 12.8f) || (fabsf(py) > 12.8f);
        px = outb ? 0.0f : px;
        py = outb ? 0.0f : py;
        int xi = bin_idx(px), yi = bin_idx(py);
        atomicOr(&s_mask[xi * 4 + (yi >> 5)], 1u << (yi & 31));
      }
    }
    __syncthreads();

    // ---- conv 5x5/s2 (LDS weights), exact R7 op order ----
    for (int p = tid; p < kOO; p += WGSZ) {
      int oy = p >> 6, ox = p & 63;
      unsigned occ = 0u;
      for (int ky = 0; ky < 5; ++ky) {
        int y = 2 * oy - 2 + ky;
        if ((unsigned)y >= 128u) continue;
        const unsigned* row = &s_mask[y * 4];
        for (int kx = 0; kx < 5; ++kx) {
          int x = 2 * ox - 2 + kx;
          if ((unsigned)x >= 128u) continue;
          if ((row[x >> 5] >> (x & 31)) & 1u) occ |= 1u << (ky * 5 + kx);
        }
      }
      float csum = 0.0f;
      for (int o = 0; o < 8; ++o) {
        float acc = 0.0f;
        const float* wo = s_cw + o * 100;
        for (int ci = 0; ci < 4; ++ci) {
          const float* wc = wo + ci * 25;
          #pragma unroll
          for (int t = 0; t < 25; ++t)
            if (occ & (1u << t)) acc = __fadd_rn(acc, wc[t]);
        }
        float th = tanhf(acc);
        csum = (o == 0) ? th : __fadd_rn(csum, th);
      }
      s_conv[p] = csum;
    }
    __syncthreads();

    // ---- ela hidden (K=3) ----
    if (tid < kH) {
      const float* w1r = ela_w1 + (st * kH + tid) * 3;
      float h = fmaf(s_anchor[2], w1r[2],
                fmaf(s_anchor[1], w1r[1], __fmul_rn(s_anchor[0], w1r[0])));
      s_elah[tid] = fmaxf(h, 0.0f);
    }
    __syncthreads();
    // ---- ela out + elm hidden (K=4096 float4 deep-unroll) ----
    if (tid < kH) {
      s_elao[tid] = dot256(ela_w2 + (st * kH + tid) * kH, s_elah);
      const float4* wr = (const float4*)(elm_w1 + (st * kH + tid) * kOO);
      const float4* xr = (const float4*)s_conv;
      float acc2 = 0.0f;
      #pragma unroll 16
      for (int i = 0; i < 1024; ++i) {
        float4 wv = wr[i], xv = xr[i];
        acc2 = fmaf(wv.x, xv.x, acc2);
        acc2 = fmaf(wv.y, xv.y, acc2);
        acc2 = fmaf(wv.z, xv.z, acc2);
        acc2 = fmaf(wv.w, xv.w, acc2);
      }
      s_elmh[tid] = fmaxf(acc2, 0.0f);
    }
    __syncthreads();
    // ---- elm out ----
    if (tid < kH) {
      s_elmo[tid] = dot256(elm_w2 + (st * kH + tid) * kH, s_elmh);
    }
    __syncthreads();
    // ---- ebl hidden (K=512, single ascending chain across concat) ----
    if (tid < kH) {
      const float* wr = ebl_w1 + (st * kH + tid) * 512;
      const float4* w4 = (const float4*)wr;
      const float4* xa = (const float4*)s_elao;
      const float4* xm = (const float4*)s_elmo;
      float acc = 0.0f;
      #pragma unroll
      for (int i = 0; i < 64; ++i) {
        float4 wv = w4[i], xv = xa[i];
        acc = fmaf(wv.x, xv.x, acc); acc = fmaf(wv.y, xv.y, acc);
        acc = fmaf(wv.z, xv.z, acc); acc = fmaf(wv.w, xv.w, acc);
      }
      #pragma unroll
      for (int i = 0; i < 64; ++i) {
        float4 wv = w4[64 + i], xv = xm[i];
        acc = fmaf(wv.x, xv.x, acc); acc = fmaf(wv.y, xv.y, acc);
        acc = fmaf(wv.z, xv.z, acc); acc = fmaf(wv.w, xv.w, acc);
      }
      s_eblh[tid] = fmaxf(acc, 0.0f);
    }
    __syncthreads();
    // ---- ebl out ----
    if (tid < kH) {
      s_eblo[tid] = dot256(ebl_w2 + (st * kH + tid) * kH, s_eblh);
    }
    __syncthreads();

    // ---- LSTM layer 0: g = fl(x@wih^T) + fl(h@whh^T) ----
    {
      const float* wf = lstm_wih + ((st * 2 + 0) * 1024 + tid) * kH;
      const float* wh = lstm_whh + ((st * 2 + 0) * 1024 + tid) * kH;
      float A = dot256(wf, s_eblo);
      float B = a0f ? sum256(wh) : dot256(wh, s_h0);
      s_gate[tid] = __fadd_rn(A, B);
    }
    __syncthreads();
    if (tid < kH) {
      float gi = s_gate[tid], gf = s_gate[256 + tid];
      float gg = s_gate[512 + tid], go = s_gate[768 + tid];
      float cprev = a0f ? 1.0f : s_c0[tid];
      float cl = __fadd_rn(__fmul_rn(sig_np(gf), cprev),
                           __fmul_rn(sig_np(gi), tanhf(gg)));
      float hl = __fmul_rn(sig_np(go), tanhf(cl));
      s_c0[tid] = cl; s_h0[tid] = hl;
    }
    __syncthreads();

    // ---- LSTM layer 1 ----
    {
      const float* wf = lstm_wih + ((st * 2 + 1) * 1024 + tid) * kH;
      const float* wh = lstm_whh + ((st * 2 + 1) * 1024 + tid) * kH;
      float A = dot256(wf, s_h0);
      float B = a0f ? sum256(wh) : dot256(wh, s_h1);
      s_gate[tid] = __fadd_rn(A, B);
    }
    __syncthreads();
    if (tid < kH) {
      float gi = s_gate[tid], gf = s_gate[256 + tid];
      float gg = s_gate[512 + tid], go = s_gate[768 + tid];
      float cprev = a0f ? 1.0f : s_c1[tid];
      float cl = __fadd_rn(__fmul_rn(sig_np(gf), cprev),
                           __fmul_rn(sig_np(gi), tanhf(gg)));
      float hl = __fmul_rn(sig_np(go), tanhf(cl));
      s_c1[tid] = cl; s_h1[tid] = hl;
    }
    __syncthreads();

    // ---- LayerNorm (numpy pairwise) + r ----
    if (tid == 0) s_mu = __fdiv_rn(np_sum256(s_h1), 256.0f);
    __syncthreads();
    if (tid < kH) {
      float d = __fadd_rn(s_h1[tid], -s_mu);
      s_tmp[tid] = d;
      s_tmp[256 + tid] = __fmul_rn(d, d);
    }
    __syncthreads();
    if (tid == 0) {
      float v = __fdiv_rn(np_sum256(s_tmp + 256), 256.0f);
      s_den = __fsqrt_rn(__fadd_rn(v, 1e-5f));
    }
    __syncthreads();
    if (tid < kH) {
      float r = __fadd_rn(__fdiv_rn(s_tmp[tid], s_den), s_eblo[tid]);
      s_r[tid] = fmaxf(r, 0.0f);
    }
    __syncthreads();

    // ---- dm/dv hidden (2 independent chains per thread) ----
    if (tid < kH) {
      s_dmh[tid] = fmaxf(dot256(dm_w1 + (st * kH + tid) * kH, s_r), 0.0f);
      s_dvh[tid] = fmaxf(dot256(dv_w1 + (st * kH + tid) * kH, s_r), 0.0f);
    }
    __syncthreads();

    // ---- heads ----
    if (tid < 6) {
      int d = tid % 3; bool isv = tid >= 3;
      s_g6[tid] = dot256(((isv ? dv_w2 : dm_w2) + (st * 3 + d) * kH),
                         (isv ? s_dvh : s_dmh));
    }
    __syncthreads();

    // ---- anchor update + outputs ----
    if (tid == 0) {
      const float dlmf[3] = {2.0f, 2.0f, 0.5f};
      for (int d = 0; d < 3; ++d) {
        float avn = __fadd_rn(s_anchor[d], __fmul_rn(tanhf(s_g6[d]), dlmf[d]));
        float vvn = __fmul_rn(sig_np(s_g6[3 + d]), 0.1f);
        s_anchor[d] = avn;
        int o = ((b * 4 + st) * 8 + (a + 1)) * 3 + d;
        g_out[o] = avn;
        g_out[6144 + o] = vvn;
        if (a == 6 && st < 3) {
          int o2 = ((b * 4 + st + 1) * 8 + 0) * 3 + d;
          g_out[o2] = avn;
          g_out[6144 + o2] = vvn;
        }
      }
      s_cs[0] = (float)cos((double)s_anchor[2]);
      s_cs[1] = (float)sin((double)s_anchor[2]);
    }
    __syncthreads();
  }
}

extern "C" void kernel_launch(void* const* d_in, const int* in_sizes, int n_in,
                              void* d_out, int out_size, void* d_ws, size_t ws_size,
                              hipStream_t stream) {
  (void)in_sizes; (void)n_in; (void)out_size; (void)d_ws; (void)ws_size;
  planner_kernel<<<dim3(NWG), dim3(WGSZ), 0, stream>>>(
      (const float*)d_in[0],  (const float*)d_in[1],  (const float*)d_in[2],
      (const float*)d_in[3],  (const float*)d_in[4],  (const float*)d_in[5],
      (const float*)d_in[6],  (const float*)d_in[7],  (const float*)d_in[8],
      (const float*)d_in[9],  (const float*)d_in[10], (const float*)d_in[11],
      (const float*)d_in[12], (const float*)d_in[13], (const float*)d_in[14],
      (float*)d_out);
}

// Round 9
// 11307.469 us; speedup vs baseline: 1.5428x; 1.5428x over previous
//
#include <hip/hip_runtime.h>

#define WGSZ 1024
#define NWG  64

namespace {
constexpr int kN = 2048, kH = 256, kOO = 4096, kGW = 512;
}

// np.argmin(|centers - v|), first index on tie; centers in exact np fp32 order.
__device__ __forceinline__ int bin_idx(float v) {
  float t = fmaf(v, 5.0f, 63.5f);
  int i0 = (int)floorf(t);
  int c0 = i0 - 1; c0 = c0 < 0 ? 0 : (c0 > 127 ? 127 : c0);
  int c1 = i0;     c1 = c1 < 0 ? 0 : (c1 > 127 ? 127 : c1);
  int c2 = i0 + 1; c2 = c2 < 0 ? 0 : (c2 > 127 ? 127 : c2);
  float d0 = fabsf(__fmul_rn(__fadd_rn((float)(c0 - 64), 0.5f), 0.2f) - v);
  float d1 = fabsf(__fmul_rn(__fadd_rn((float)(c1 - 64), 0.5f), 0.2f) - v);
  float d2 = fabsf(__fmul_rn(__fadd_rn((float)(c2 - 64), 0.5f), 0.2f) - v);
  int best = c0; float bd = d0;
  if (d1 < bd) { bd = d1; best = c1; }
  if (d2 < bd) { bd = d2; best = c2; }
  return best;
}

// numpy pairwise_sum, exact replication for n=128.
__device__ __forceinline__ float np_pw128(const float* a) {
  float r0=a[0],r1=a[1],r2=a[2],r3=a[3],r4=a[4],r5=a[5],r6=a[6],r7=a[7];
  for (int i = 8; i < 128; i += 8) {
    r0=__fadd_rn(r0,a[i+0]); r1=__fadd_rn(r1,a[i+1]);
    r2=__fadd_rn(r2,a[i+2]); r3=__fadd_rn(r3,a[i+3]);
    r4=__fadd_rn(r4,a[i+4]); r5=__fadd_rn(r5,a[i+5]);
    r6=__fadd_rn(r6,a[i+6]); r7=__fadd_rn(r7,a[i+7]);
  }
  return __fadd_rn(__fadd_rn(__fadd_rn(r0,r1),__fadd_rn(r2,r3)),
                   __fadd_rn(__fadd_rn(r4,r5),__fadd_rn(r6,r7)));
}
__device__ __forceinline__ float np_sum256(const float* a) {
  return __fadd_rn(np_pw128(a), np_pw128(a + 128));
}

__device__ __forceinline__ float sig_np(float x) {
  return __fdiv_rn(1.0f, __fadd_rn(1.0f, expf(-x)));
}

// Exact ascending-k K=256 dot; float4 loads, unroll 8 (no spill at 128 VGPR).
__device__ __forceinline__ float dot256(const float* __restrict__ w, const float* x) {
  const float4* w4 = (const float4*)w;
  const float4* x4 = (const float4*)x;
  float acc = 0.0f;
  #pragma unroll 8
  for (int i = 0; i < 64; ++i) {
    float4 wv = w4[i], xv = x4[i];
    acc = fmaf(wv.x, xv.x, acc);
    acc = fmaf(wv.y, xv.y, acc);
    acc = fmaf(wv.z, xv.z, acc);
    acc = fmaf(wv.w, xv.w, acc);
  }
  return acc;
}
// Exact ascending plain sum of 256 weights (h = ones case).
__device__ __forceinline__ float sum256(const float* __restrict__ w) {
  const float4* w4 = (const float4*)w;
  float acc = 0.0f;
  #pragma unroll 8
  for (int i = 0; i < 64; ++i) {
    float4 wv = w4[i];
    acc = __fadd_rn(acc, wv.x);
    acc = __fadd_rn(acc, wv.y);
    acc = __fadd_rn(acc, wv.z);
    acc = __fadd_rn(acc, wv.w);
  }
  return acc;
}

// One WG of 16 waves per CU: 4 waves/EU -> 128 VGPR budget, no spills.
__global__ __launch_bounds__(WGSZ, 4) void planner_kernel(
    const float* __restrict__ inp_start, const float* __restrict__ map_pts,
    const float* __restrict__ ela_w1, const float* __restrict__ ela_w2,
    const float* __restrict__ conv_w, const float* __restrict__ elm_w1,
    const float* __restrict__ elm_w2, const float* __restrict__ ebl_w1,
    const float* __restrict__ ebl_w2, const float* __restrict__ lstm_wih,
    const float* __restrict__ lstm_whh, const float* __restrict__ dm_w1,
    const float* __restrict__ dm_w2, const float* __restrict__ dv_w1,
    const float* __restrict__ dv_w2, float* __restrict__ g_out) {
  const int b   = blockIdx.x;
  const int tid = threadIdx.x;

  __shared__ unsigned s_mask[kGW];
  __shared__ __align__(16) float s_conv[kOO];   // 16KB
  __shared__ __align__(16) float s_cw[800];     // conv weights for stage (LDS)
  __shared__ __align__(16) float s_elah[kH], s_elao[kH], s_elmh[kH], s_elmo[kH];
  __shared__ __align__(16) float s_eblh[kH], s_eblo[kH];
  __shared__ __align__(16) float s_h0[kH], s_c0[kH], s_h1[kH], s_c1[kH];
  __shared__ __align__(16) float s_gate[1024];
  __shared__ __align__(16) float s_tmp[512];    // LN: d, d^2
  __shared__ __align__(16) float s_r[kH], s_dmh[kH], s_dvh[kH];
  __shared__ float s_anchor[3], s_cs[2], s_g6[6];
  __shared__ float s_mu, s_den;

  // ---- init ----
  if (tid == 0) {
    float a2 = inp_start[b * 3 + 2];
    s_anchor[0] = inp_start[b * 3 + 0];
    s_anchor[1] = inp_start[b * 3 + 1];
    s_anchor[2] = a2;
    s_cs[0] = (float)cos((double)a2);
    s_cs[1] = (float)sin((double)a2);
  }
  if (tid < 3) {
    g_out[b * 96 + tid] = inp_start[b * 3 + tid];
    g_out[6144 + b * 96 + tid] = 0.01f;
  }
  __syncthreads();

  // ================= 28 sequential steps, all batch-local =================
  for (int k = 0; k < 28; ++k) {
    const int st = k / 7, a = k % 7;
    const bool a0f = (a == 0);

    // ---- OGM + conv-weight staging ----
    for (int w = tid; w < kGW; w += WGSZ) s_mask[w] = 0u;
    for (int w = tid; w < 800; w += WGSZ) s_cw[w] = conv_w[st * 800 + w];
    __syncthreads();
    {
      float ax = s_anchor[0], ay = s_anchor[1], cc = s_cs[0], ss = s_cs[1];
      for (int n = tid; n < kN; n += WGSZ) {
        float mx = __fadd_rn(map_pts[n],      -ax);
        float my = __fadd_rn(map_pts[kN + n], -ay);
        float px = fmaf(ss, my, __fmul_rn(cc, mx));
        float py = fmaf(cc, my, -__fmul_rn(ss, mx));
        bool outb = (fabsf(px) > 12.8f) || (fabsf(py) > 12.8f);
        px = outb ? 0.0f : px;
        py = outb ? 0.0f : py;
        int xi = bin_idx(px), yi = bin_idx(py);
        atomicOr(&s_mask[xi * 4 + (yi >> 5)], 1u << (yi & 31));
      }
    }
    __syncthreads();

    // ---- conv 5x5/s2 (LDS weights), exact R7 op order ----
    for (int p = tid; p < kOO; p += WGSZ) {
      int oy = p >> 6, ox = p & 63;
      unsigned occ = 0u;
      for (int ky = 0; ky < 5; ++ky) {
        int y = 2 * oy - 2 + ky;
        if ((unsigned)y >= 128u) continue;
        const unsigned* row = &s_mask[y * 4];
        for (int kx = 0; kx < 5; ++kx) {
          int x = 2 * ox - 2 + kx;
          if ((unsigned)x >= 128u) continue;
          if ((row[x >> 5] >> (x & 31)) & 1u) occ |= 1u << (ky * 5 + kx);
        }
      }
      float csum = 0.0f;
      for (int o = 0; o < 8; ++o) {
        float acc = 0.0f;
        const float* wo = s_cw + o * 100;
        for (int ci = 0; ci < 4; ++ci) {
          const float* wc = wo + ci * 25;
          #pragma unroll
          for (int t = 0; t < 25; ++t)
            if (occ & (1u << t)) acc = __fadd_rn(acc, wc[t]);
        }
        float th = tanhf(acc);
        csum = (o == 0) ? th : __fadd_rn(csum, th);
      }
      s_conv[p] = csum;
    }
    __syncthreads();

    // ---- ela hidden (K=3) ----
    if (tid < kH) {
      const float* w1r = ela_w1 + (st * kH + tid) * 3;
      float h = fmaf(s_anchor[2], w1r[2],
                fmaf(s_anchor[1], w1r[1], __fmul_rn(s_anchor[0], w1r[0])));
      s_elah[tid] = fmaxf(h, 0.0f);
    }
    __syncthreads();
    // ---- ela out + elm hidden (K=4096 float4, unroll 8) ----
    if (tid < kH) {
      s_elao[tid] = dot256(ela_w2 + (st * kH + tid) * kH, s_elah);
      const float4* wr = (const float4*)(elm_w1 + (st * kH + tid) * kOO);
      const float4* xr = (const float4*)s_conv;
      float acc2 = 0.0f;
      #pragma unroll 8
      for (int i = 0; i < 1024; ++i) {
        float4 wv = wr[i], xv = xr[i];
        acc2 = fmaf(wv.x, xv.x, acc2);
        acc2 = fmaf(wv.y, xv.y, acc2);
        acc2 = fmaf(wv.z, xv.z, acc2);
        acc2 = fmaf(wv.w, xv.w, acc2);
      }
      s_elmh[tid] = fmaxf(acc2, 0.0f);
    }
    __syncthreads();
    // ---- elm out ----
    if (tid < kH) {
      s_elmo[tid] = dot256(elm_w2 + (st * kH + tid) * kH, s_elmh);
    }
    __syncthreads();
    // ---- ebl hidden (K=512, single ascending chain across concat) ----
    if (tid < kH) {
      const float* wr = ebl_w1 + (st * kH + tid) * 512;
      const float4* w4 = (const float4*)wr;
      const float4* xa = (const float4*)s_elao;
      const float4* xm = (const float4*)s_elmo;
      float acc = 0.0f;
      #pragma unroll 8
      for (int i = 0; i < 64; ++i) {
        float4 wv = w4[i], xv = xa[i];
        acc = fmaf(wv.x, xv.x, acc); acc = fmaf(wv.y, xv.y, acc);
        acc = fmaf(wv.z, xv.z, acc); acc = fmaf(wv.w, xv.w, acc);
      }
      #pragma unroll 8
      for (int i = 0; i < 64; ++i) {
        float4 wv = w4[64 + i], xv = xm[i];
        acc = fmaf(wv.x, xv.x, acc); acc = fmaf(wv.y, xv.y, acc);
        acc = fmaf(wv.z, xv.z, acc); acc = fmaf(wv.w, xv.w, acc);
      }
      s_eblh[tid] = fmaxf(acc, 0.0f);
    }
    __syncthreads();
    // ---- ebl out ----
    if (tid < kH) {
      s_eblo[tid] = dot256(ebl_w2 + (st * kH + tid) * kH, s_eblh);
    }
    __syncthreads();

    // ---- LSTM layer 0: g = fl(x@wih^T) + fl(h@whh^T) ----
    {
      const float* wf = lstm_wih + ((st * 2 + 0) * 1024 + tid) * kH;
      const float* wh = lstm_whh + ((st * 2 + 0) * 1024 + tid) * kH;
      float A = dot256(wf, s_eblo);
      float B = a0f ? sum256(wh) : dot256(wh, s_h0);
      s_gate[tid] = __fadd_rn(A, B);
    }
    __syncthreads();
    if (tid < kH) {
      float gi = s_gate[tid], gf = s_gate[256 + tid];
      float gg = s_gate[512 + tid], go = s_gate[768 + tid];
      float cprev = a0f ? 1.0f : s_c0[tid];
      float cl = __fadd_rn(__fmul_rn(sig_np(gf), cprev),
                           __fmul_rn(sig_np(gi), tanhf(gg)));
      float hl = __fmul_rn(sig_np(go), tanhf(cl));
      s_c0[tid] = cl; s_h0[tid] = hl;
    }
    __syncthreads();

    // ---- LSTM layer 1 ----
    {
      const float* wf = lstm_wih + ((st * 2 + 1) * 1024 + tid) * kH;
      const float* wh = lstm_whh + ((st * 2 + 1) * 1024 + tid) * kH;
      float A = dot256(wf, s_h0);
      float B = a0f ? sum256(wh) : dot256(wh, s_h1);
      s_gate[tid] = __fadd_rn(A, B);
    }
    __syncthreads();
    if (tid < kH) {
      float gi = s_gate[tid], gf = s_gate[256 + tid];
      float gg = s_gate[512 + tid], go = s_gate[768 + tid];
      float cprev = a0f ? 1.0f : s_c1[tid];
      float cl = __fadd_rn(__fmul_rn(sig_np(gf), cprev),
                           __fmul_rn(sig_np(gi), tanhf(gg)));
      float hl = __fmul_rn(sig_np(go), tanhf(cl));
      s_c1[tid] = cl; s_h1[tid] = hl;
    }
    __syncthreads();

    // ---- LayerNorm (numpy pairwise) + r ----
    if (tid == 0) s_mu = __fdiv_rn(np_sum256(s_h1), 256.0f);
    __syncthreads();
    if (tid < kH) {
      float d = __fadd_rn(s_h1[tid], -s_mu);
      s_tmp[tid] = d;
      s_tmp[256 + tid] = __fmul_rn(d, d);
    }
    __syncthreads();
    if (tid == 0) {
      float v = __fdiv_rn(np_sum256(s_tmp + 256), 256.0f);
      s_den = __fsqrt_rn(__fadd_rn(v, 1e-5f));
    }
    __syncthreads();
    if (tid < kH) {
      float r = __fadd_rn(__fdiv_rn(s_tmp[tid], s_den), s_eblo[tid]);
      s_r[tid] = fmaxf(r, 0.0f);
    }
    __syncthreads();

    // ---- dm/dv hidden ----
    if (tid < kH) {
      s_dmh[tid] = fmaxf(dot256(dm_w1 + (st * kH + tid) * kH, s_r), 0.0f);
      s_dvh[tid] = fmaxf(dot256(dv_w1 + (st * kH + tid) * kH, s_r), 0.0f);
    }
    __syncthreads();

    // ---- heads ----
    if (tid < 6) {
      int d = tid % 3; bool isv = tid >= 3;
      s_g6[tid] = dot256(((isv ? dv_w2 : dm_w2) + (st * 3 + d) * kH),
                         (isv ? s_dvh : s_dmh));
    }
    __syncthreads();

    // ---- anchor update + outputs ----
    if (tid == 0) {
      const float dlmf[3] = {2.0f, 2.0f, 0.5f};
      for (int d = 0; d < 3; ++d) {
        float avn = __fadd_rn(s_anchor[d], __fmul_rn(tanhf(s_g6[d]), dlmf[d]));
        float vvn = __fmul_rn(sig_np(s_g6[3 + d]), 0.1f);
        s_anchor[d] = avn;
        int o = ((b * 4 + st) * 8 + (a + 1)) * 3 + d;
        g_out[o] = avn;
        g_out[6144 + o] = vvn;
        if (a == 6 && st < 3) {
          int o2 = ((b * 4 + st + 1) * 8 + 0) * 3 + d;
          g_out[o2] = avn;
          g_out[6144 + o2] = vvn;
        }
      }
      s_cs[0] = (float)cos((double)s_anchor[2]);
      s_cs[1] = (float)sin((double)s_anchor[2]);
    }
    __syncthreads();
  }
}

extern "C" void kernel_launch(void* const* d_in, const int* in_sizes, int n_in,
                              void* d_out, int out_size, void* d_ws, size_t ws_size,
                              hipStream_t stream) {
  (void)in_sizes; (void)n_in; (void)out_size; (void)d_ws; (void)ws_size;
  planner_kernel<<<dim3(NWG), dim3(WGSZ), 0, stream>>>(
      (const float*)d_in[0],  (const float*)d_in[1],  (const float*)d_in[2],
      (const float*)d_in[3],  (const float*)d_in[4],  (const float*)d_in[5],
      (const float*)d_in[6],  (const float*)d_in[7],  (const float*)d_in[8],
      (const float*)d_in[9],  (const float*)d_in[10], (const float*)d_in[11],
      (const float*)d_in[12], (const float*)d_in[13], (const float*)d_in[14],
      (float*)d_out);
}